// Round 8
// baseline (356.273 us; speedup 1.0000x reference)
//
#include <hip/hip_runtime.h>
#include <stdint.h>

typedef unsigned short u16;
typedef __attribute__((ext_vector_type(8))) short short8v;
typedef __attribute__((ext_vector_type(4))) short short4v;
typedef __attribute__((ext_vector_type(4))) float f32x4;

#define B_ 8
#define T_ 8192
#define H_ 256
#define M_ 65536            // B_*T_
#define MH 16777216         // M_*H_
#define NCH 256             // chunks along T
#define CHL 32              // T_/NCH
#define NCHAN 4096          // 2*B_*H_

__device__ __forceinline__ u16 f2bf(float f) {
  union { float f; uint32_t u; } v; v.f = f;
  return (u16)((v.u + 0x7FFFu + ((v.u >> 16) & 1u)) >> 16);
}
__device__ __forceinline__ float bf2f(u16 s) {
  union { uint32_t u; float f; } v; v.u = ((uint32_t)s) << 16;
  return v.f;
}
__device__ __forceinline__ float sigm(float x) {
  return __fdividef(1.0f, 1.0f + __expf(-x));
}
__device__ __forceinline__ float tanhfast(float x) {
  return 1.0f - __fdividef(2.0f, __expf(2.0f * x) + 1.0f);
}

// A_t, b_t of the linearized recurrence. A at t=0 is irrelevant downstream
// (h_{-1}=0 zeroes its contribution in P/q/h), so no special-casing.
__device__ __forceinline__ void compute_Ab(float zf, float ag, float hp, float dr,
                                           float& Aa, float& bb) {
  const float u = sigm(ag);
  const float g = u * (1.f - u) * dr;
  Aa = u + (hp - zf) * g;
  bb = u * hp + (1.f - u) * zf - Aa * hp;
}

__device__ __forceinline__ void g2l16(const void* g, void* l) {
  __builtin_amdgcn_global_load_lds((const __attribute__((address_space(1))) void*)g,
                                   (__attribute__((address_space(3))) void*)l, 16, 0, 0);
}
// u16 index into a swizzled [64][256] bf16 tile (512B rows; 16B units XOR'd by row&7)
__device__ __forceinline__ int zts(int row, int col) {
  return row * 256 + ((((col >> 3) ^ (row & 7)) << 3) | (col & 7));
}

// ---------------- prep: cvt x -> bf16, cvt weights -> bf16 ----------------
__global__ __launch_bounds__(256) void prep_kernel(
    const float* __restrict__ x, u16* __restrict__ xf,
    const float* __restrict__ w0, const float* __restrict__ w1, const float* __restrict__ w2,
    const float* __restrict__ w3, const float* __restrict__ w4, const float* __restrict__ w5,
    u16* __restrict__ wbf) {
  const int bx = blockIdx.x;
  const float* src;
  u16* dst;
  size_t i;
  if (bx < 8192) {
    i = ((size_t)bx * 256 + threadIdx.x) * 8;
    src = x; dst = xf;
  } else {
    const int r = bx - 8192;
    const int wsel = r >> 5, blk = r & 31;
    src = (wsel == 0) ? w0 : (wsel == 1) ? w1 : (wsel == 2) ? w2
        : (wsel == 3) ? w3 : (wsel == 4) ? w4 : w5;
    dst = wbf + (size_t)wsel * 65536;
    i = ((size_t)blk * 256 + threadIdx.x) * 8;
  }
  const float4* s4 = (const float4*)(src + i);
  float4 a = s4[0], b = s4[1];
  short8v o;
  o[0] = (short)f2bf(a.x); o[1] = (short)f2bf(a.y);
  o[2] = (short)f2bf(a.z); o[3] = (short)f2bf(a.w);
  o[4] = (short)f2bf(b.x); o[5] = (short)f2bf(b.y);
  o[6] = (short)f2bf(b.z); o[7] = (short)f2bf(b.w);
  *(short8v*)(dst + i) = o;
}

// ---------------- zzu: z = tanh(x Win^T + b_in); zu = z Uz^T + b_u; fused scan-p1 ----
// Block: 64 rows x 256 cols, 256 threads (4 waves, wave w owns cols n0=w*64).
// LDS (64KB): Bst [0,32K) | Ast [32K,40K) (stage1 only) | ztile [32K,64K) (after stage1)
//             zutile [0,32K) (after stage2, aliases Bst).
__global__ __launch_bounds__(256) void zzu_k(
    const u16* __restrict__ xf, const u16* __restrict__ wbf,
    const float* __restrict__ bin0, const float* __restrict__ bin1,
    const float* __restrict__ bu0, const float* __restrict__ bu1,
    const float* __restrict__ Wf_rec, const float* __restrict__ Wb_rec,
    u16* __restrict__ zout, u16* __restrict__ zuout,
    float* __restrict__ Pout, float* __restrict__ qout) {
  __shared__ __align__(16) char lds[65536];
  const int dir = blockIdx.z;
  const int tm = blockIdx.x;                  // 0..1023, rows tm*64..+64
  const char* Win = (const char*)(wbf + (size_t)dir * 196608);
  const char* Uz  = (const char*)(wbf + (size_t)dir * 196608 + 65536);
  const float* bin = dir ? bin1 : bin0;
  const float* bu  = dir ? bu1 : bu0;
  const int tid = threadIdx.x, l = tid & 63, w = tid >> 6;
  const int n0 = w * 64;
  const size_t zoff = (size_t)dir * MH;
  u16* zt  = (u16*)(lds + 32768);
  u16* zut = (u16*)lds;

  f32x4 vzero = {0.f, 0.f, 0.f, 0.f};
  f32x4 acc[4][4];
#pragma unroll
  for (int i = 0; i < 4; ++i)
#pragma unroll
    for (int j = 0; j < 4; ++j) acc[i][j] = vzero;

  // ---- stage 1: z = x Win^T ----
#pragma unroll
  for (int k0 = 0; k0 < 256; k0 += 64) {
    // stage A [64x64] (2 issues) + B [256x64] (8 issues); linear LDS dest,
    // pre-swizzled global source column (T2, rule #21)
#pragma unroll
    for (int is = 0; is < 2; ++is) {
      const int o = is * 4096 + tid * 16;
      const int row = o >> 7;                 // 0..63
      const int cb = (o & 127) ^ ((row & 7) << 4);
      int rA = tm * 64 + row;
      if (dir) { int bb = rA >> 13; int t = rA & 8191; rA = (bb << 13) + (8191 - t); }
      g2l16((const char*)xf + (size_t)rA * 512 + k0 * 2 + cb,
            lds + 32768 + is * 4096 + w * 1024);
    }
#pragma unroll
    for (int is = 0; is < 8; ++is) {
      const int o = is * 4096 + tid * 16;
      const int row = o >> 7;                 // 0..255
      const int cb = (o & 127) ^ ((row & 7) << 4);
      g2l16(Win + (size_t)row * 512 + k0 * 2 + cb, lds + is * 4096 + w * 1024);
    }
    __syncthreads();
#pragma unroll
    for (int kk = 0; kk < 2; ++kk) {
      const int colb = (kk * 64 + (l >> 4) * 16) ^ ((l & 7) << 4);
      short8v av[4], bv[4];
#pragma unroll
      for (int i = 0; i < 4; ++i) {
        av[i] = *(const short8v*)(lds + 32768 + (i * 16 + (l & 15)) * 128 + colb);
        bv[i] = *(const short8v*)(lds + (n0 + i * 16 + (l & 15)) * 128 + colb);
      }
#pragma unroll
      for (int i = 0; i < 4; ++i)
#pragma unroll
        for (int j = 0; j < 4; ++j)
          acc[i][j] = __builtin_amdgcn_mfma_f32_16x16x32_bf16(av[i], bv[j], acc[i][j], 0, 0, 0);
    }
    __syncthreads();
  }

  // ---- epilogue 1: z tile (swizzled) ----
#pragma unroll
  for (int j = 0; j < 4; ++j) {
    const int col = n0 + j * 16 + (l & 15);
    const float bv = bin[col];
#pragma unroll
    for (int i = 0; i < 4; ++i)
#pragma unroll
      for (int r = 0; r < 4; ++r) {
        const int row = (l >> 4) * 4 + i * 16 + r;
        zt[zts(row, col)] = f2bf(tanhfast(acc[i][j][r] + bv));
      }
  }
  __syncthreads();

  // coalesced z store (read swizzled tile, write linear global)
  {
    const int row = tid >> 2;
    const int ub = (tid & 3) * 8;
    char* g = (char*)(zout + zoff) + (size_t)(tm * 64 + row) * 512;
#pragma unroll
    for (int q = 0; q < 8; ++q) {
      const int u = ub + q;
      short8v v = *(const short8v*)((const char*)zt + row * 512 + ((u ^ (row & 7)) << 4));
      *(short8v*)(g + u * 16) = v;
    }
  }

  // ---- stage 2: zu = z Uz^T  (A from LDS z-tile) ----
#pragma unroll
  for (int i = 0; i < 4; ++i)
#pragma unroll
    for (int j = 0; j < 4; ++j) acc[i][j] = vzero;
#pragma unroll
  for (int k0 = 0; k0 < 256; k0 += 64) {
#pragma unroll
    for (int is = 0; is < 8; ++is) {
      const int o = is * 4096 + tid * 16;
      const int row = o >> 7;
      const int cb = (o & 127) ^ ((row & 7) << 4);
      g2l16(Uz + (size_t)row * 512 + k0 * 2 + cb, lds + is * 4096 + w * 1024);
    }
    __syncthreads();
#pragma unroll
    for (int kk = 0; kk < 2; ++kk) {
      short8v av[4], bv[4];
#pragma unroll
      for (int i = 0; i < 4; ++i) {
        const int row = i * 16 + (l & 15);
        const int u = (k0 >> 3) + kk * 4 + (l >> 4);
        av[i] = *(const short8v*)((const char*)zt + row * 512 + ((u ^ (row & 7)) << 4));
        const int colb = (kk * 64 + (l >> 4) * 16) ^ ((l & 7) << 4);
        bv[i] = *(const short8v*)(lds + (n0 + i * 16 + (l & 15)) * 128 + colb);
      }
#pragma unroll
      for (int i = 0; i < 4; ++i)
#pragma unroll
        for (int j = 0; j < 4; ++j)
          acc[i][j] = __builtin_amdgcn_mfma_f32_16x16x32_bf16(av[i], bv[j], acc[i][j], 0, 0, 0);
    }
    __syncthreads();
  }

  // ---- epilogue 2: zu tile ----
#pragma unroll
  for (int j = 0; j < 4; ++j) {
    const int col = n0 + j * 16 + (l & 15);
    const float bv = bu[col];
#pragma unroll
    for (int i = 0; i < 4; ++i)
#pragma unroll
      for (int r = 0; r < 4; ++r) {
        const int row = (l >> 4) * 4 + i * 16 + r;
        zut[zts(row, col)] = f2bf(acc[i][j][r] + bv);
      }
  }
  __syncthreads();

  // coalesced zu store
  {
    const int row = tid >> 2;
    const int ub = (tid & 3) * 8;
    char* g = (char*)(zuout + zoff) + (size_t)(tm * 64 + row) * 512;
#pragma unroll
    for (int q = 0; q < 8; ++q) {
      const int u = ub + q;
      short8v v = *(const short8v*)((const char*)zut + row * 512 + ((u ^ (row & 7)) << 4));
      *(short8v*)(g + u * 16) = v;
    }
  }

  // ---- fused scan pass-1 (iter 1): zf, ag both from LDS ----
  {
    const int h = tid;
    const float dr = (dir ? Wb_rec : Wf_rec)[h * 257];
    const int b = tm >> 7;
    const int c0 = (tm & 127) * 2;
    const int ch = (dir * 8 + b) * 256 + h;
#pragma unroll
    for (int cc = 0; cc < 2; ++cc) {
      float Pv = 1.f, qv = 0.f;
#pragma unroll 4
      for (int it = 0; it < CHL; ++it) {
        const int row = cc * 32 + it;
        const float zf = bf2f(zt[zts(row, h)]);
        const float ag = bf2f(zut[zts(row, h)]);
        float Aa, bbv;
        compute_Ab(zf, ag, 0.f, dr, Aa, bbv);
        qv = Aa * qv + bbv;
        Pv *= Aa;
      }
      Pout[(size_t)(c0 + cc) * NCHAN + ch] = Pv;
      qout[(size_t)(c0 + cc) * NCHAN + ch] = qv;
    }
  }
}

// ---------------- s1zuh: p3<1> tile -> s1 (LDS+global); zuh = zu + s1 Wrec^T; fused p1 ----
// LDS (64KB): Bst [0,32K) | s1tile [32K,64K) ; zuhtile [0,32K) after gemm.
__global__ __launch_bounds__(256) void s1zuh_k(
    const u16* __restrict__ zb, u16* __restrict__ zub,    // zub: in zu, out zuh (in-place)
    const u16* __restrict__ wbf,
    const float* __restrict__ Wf_rec, const float* __restrict__ Wb_rec,
    const float* __restrict__ hst,
    u16* __restrict__ s1out, float* __restrict__ Pout, float* __restrict__ qout) {
  __shared__ __align__(16) char lds[65536];
  const int dir = blockIdx.z;
  const int tm = blockIdx.x;
  const char* Wr = (const char*)(wbf + (size_t)dir * 196608 + 131072);
  const int tid = threadIdx.x, l = tid & 63, w = tid >> 6;
  const int n0 = w * 64;
  const size_t zoff = (size_t)dir * MH;
  u16* s1t = (u16*)(lds + 32768);
  u16* zht = (u16*)lds;

  const int h = tid;
  const float dr = (dir ? Wb_rec : Wf_rec)[h * 257];
  const int b = tm >> 7;
  const int c0 = (tm & 127) * 2;
  const int ch = (dir * 8 + b) * 256 + h;

  // ---- step 1: h1 recurrence for this tile's 2 chunks -> shifted s1 tile ----
  s1t[zts(0, h)] = f2bf(hst[(size_t)c0 * NCHAN + ch]);
#pragma unroll
  for (int cc = 0; cc < 2; ++cc) {
    float hcur = hst[(size_t)(c0 + cc) * NCHAN + ch];
#pragma unroll 4
    for (int it = 0; it < CHL; ++it) {
      const size_t g = (size_t)(tm * 64 + cc * 32 + it) * 256 + h;
      const float zf = bf2f(zb[zoff + g]);
      const float ag = bf2f(zub[zoff + g]);
      float Aa, bbv;
      compute_Ab(zf, ag, 0.f, dr, Aa, bbv);
      hcur = Aa * hcur + bbv;
      const int rr = cc * 32 + it + 1;
      if (rr < 64) s1t[zts(rr, h)] = f2bf(hcur);
    }
  }
  __syncthreads();

  // coalesced s1 store
  {
    const int row = tid >> 2;
    const int ub = (tid & 3) * 8;
    char* g = (char*)(s1out + zoff) + (size_t)(tm * 64 + row) * 512;
#pragma unroll
    for (int q = 0; q < 8; ++q) {
      const int u = ub + q;
      short8v v = *(const short8v*)((const char*)s1t + row * 512 + ((u ^ (row & 7)) << 4));
      *(short8v*)(g + u * 16) = v;
    }
  }

  // ---- step 2: zuh = zu + s1 Wrec^T (A from LDS s1 tile) ----
  f32x4 vzero = {0.f, 0.f, 0.f, 0.f};
  f32x4 acc[4][4];
#pragma unroll
  for (int i = 0; i < 4; ++i)
#pragma unroll
    for (int j = 0; j < 4; ++j) acc[i][j] = vzero;
#pragma unroll
  for (int k0 = 0; k0 < 256; k0 += 64) {
#pragma unroll
    for (int is = 0; is < 8; ++is) {
      const int o = is * 4096 + tid * 16;
      const int row = o >> 7;
      const int cb = (o & 127) ^ ((row & 7) << 4);
      g2l16(Wr + (size_t)row * 512 + k0 * 2 + cb, lds + is * 4096 + w * 1024);
    }
    __syncthreads();
#pragma unroll
    for (int kk = 0; kk < 2; ++kk) {
      short8v av[4], bv[4];
#pragma unroll
      for (int i = 0; i < 4; ++i) {
        const int row = i * 16 + (l & 15);
        const int u = (k0 >> 3) + kk * 4 + (l >> 4);
        av[i] = *(const short8v*)((const char*)s1t + row * 512 + ((u ^ (row & 7)) << 4));
        const int colb = (kk * 64 + (l >> 4) * 16) ^ ((l & 7) << 4);
        bv[i] = *(const short8v*)(lds + (n0 + i * 16 + (l & 15)) * 128 + colb);
      }
#pragma unroll
      for (int i = 0; i < 4; ++i)
#pragma unroll
        for (int j = 0; j < 4; ++j)
          acc[i][j] = __builtin_amdgcn_mfma_f32_16x16x32_bf16(av[i], bv[j], acc[i][j], 0, 0, 0);
    }
    __syncthreads();
  }

  // epilogue: + zu (global, L2-hot) -> zuh tile
#pragma unroll
  for (int j = 0; j < 4; ++j) {
    const int col = n0 + j * 16 + (l & 15);
#pragma unroll
    for (int i = 0; i < 4; ++i)
#pragma unroll
      for (int r = 0; r < 4; ++r) {
        const int row = (l >> 4) * 4 + i * 16 + r;
        const float xv = acc[i][j][r] + bf2f(zub[zoff + (size_t)(tm * 64 + row) * 256 + col]);
        zht[zts(row, col)] = f2bf(xv);
      }
  }
  __syncthreads();

  // coalesced zuh store (in-place over zu; blocks are row-disjoint)
  {
    const int row = tid >> 2;
    const int ub = (tid & 3) * 8;
    char* g = (char*)(zub + zoff) + (size_t)(tm * 64 + row) * 512;
#pragma unroll
    for (int q = 0; q < 8; ++q) {
      const int u = ub + q;
      short8v v = *(const short8v*)((const char*)zht + row * 512 + ((u ^ (row & 7)) << 4));
      *(short8v*)(g + u * 16) = v;
    }
  }

  // ---- fused scan pass-1 (iter 2): hp, ag from LDS; zf from global (L2-warm) ----
#pragma unroll
  for (int cc = 0; cc < 2; ++cc) {
    float Pv = 1.f, qv = 0.f;
#pragma unroll 4
    for (int it = 0; it < CHL; ++it) {
      const int row = cc * 32 + it;
      const float zf = bf2f(zb[zoff + (size_t)(tm * 64 + row) * 256 + h]);
      const float hp = bf2f(s1t[zts(row, h)]);
      const float ag = bf2f(zht[zts(row, h)]);
      float Aa, bbv;
      compute_Ab(zf, ag, hp, dr, Aa, bbv);
      qv = Aa * qv + bbv;
      Pv *= Aa;
    }
    Pout[(size_t)(c0 + cc) * NCHAN + ch] = Pv;
    qout[(size_t)(c0 + cc) * NCHAN + ch] = qv;
  }
}

// ---------------- scan pass 2: exclusive scan over chunk summaries ----------------
__global__ __launch_bounds__(256) void scan_p2_kernel(const float* __restrict__ P,
                                                      const float* __restrict__ q,
                                                      float* __restrict__ hstart) {
  const int ch = blockIdx.x * 256 + threadIdx.x;    // 0..4095
  float hs = 0.f;
#pragma unroll 8
  for (int c = 0; c < NCH; ++c) {
    hstart[c * NCHAN + ch] = hs;
    hs = P[c * NCHAN + ch] * hs + q[c * NCHAN + ch];
  }
}

// ---------------- scan pass 3 (iter 2): replay chunk, emit output + h_n ----------------
__global__ __launch_bounds__(256) void scan_p3_kernel(
    const u16* __restrict__ zb, const u16* __restrict__ zub,
    const u16* __restrict__ s1b,
    const float* __restrict__ Wf_rec, const float* __restrict__ Wb_rec,
    const float* __restrict__ hstart,
    float* __restrict__ out, float* __restrict__ hn) {
  const int wid = blockIdx.x * 4 + (threadIdx.x >> 6);
  const int lane = threadIdx.x & 63;
  const int c = wid & (NCH - 1);
  const int tmp = wid >> 8;
  const int b = tmp & 7;
  const int d = tmp >> 3;
  const int h0 = lane * 4;
  const float* Wr = d ? Wb_rec : Wf_rec;
  float dr[4];
#pragma unroll
  for (int j = 0; j < 4; ++j) dr[j] = Wr[(h0 + j) * 257];
  const size_t off = (size_t)d * MH + ((size_t)b * T_ + (size_t)c * CHL) * H_ + h0;
  const u16* zp = zb + off;
  const u16* zup = zub + off;
  const u16* s1p = s1b + off;
  const int ch0 = (d * 8 + b) * 256 + h0;
  f32x4 h4 = *(const f32x4*)(hstart + (size_t)c * NCHAN + ch0);
  float hc[4] = {h4[0], h4[1], h4[2], h4[3]};
#pragma unroll 4
  for (int it = 0; it < CHL; ++it) {
    const size_t ix = (size_t)it * H_;
    short4v z4 = *(const short4v*)(zp + ix);
    short4v a4 = *(const short4v*)(zup + ix);
    short4v s4 = *(const short4v*)(s1p + ix);
#pragma unroll
    for (int j = 0; j < 4; ++j) {
      const float zf = bf2f((u16)z4[j]);
      const float ag = bf2f((u16)a4[j]);
      const float hp = bf2f((u16)s4[j]);
      float Aa, bb;
      compute_Ab(zf, ag, hp, dr[j], Aa, bb);
      hc[j] = Aa * hc[j] + bb;
    }
    const int t = c * CHL + it;
    const size_t to = (d == 0) ? ((size_t)b * T_ + t) * 512 + h0
                               : ((size_t)b * T_ + (T_ - 1 - t)) * 512 + 256 + h0;
    *(f32x4*)(out + to) = (f32x4){hc[0], hc[1], hc[2], hc[3]};
    if (t == T_ - 1)
      *(f32x4*)(hn + (size_t)(d * 8 + b) * 256 + h0) = (f32x4){hc[0], hc[1], hc[2], hc[3]};
  }
}

// ---------------- host ----------------
extern "C" void kernel_launch(void* const* d_in, const int* in_sizes, int n_in,
                              void* d_out, int out_size, void* d_ws, size_t ws_size,
                              hipStream_t stream) {
  const float* x      = (const float*)d_in[0];
  const float* Wf_in  = (const float*)d_in[1];
  const float* bf_in  = (const float*)d_in[2];
  const float* Wf_rec = (const float*)d_in[3];
  const float* Uf_z   = (const float*)d_in[4];
  const float* bf_u   = (const float*)d_in[5];
  const float* Wb_in  = (const float*)d_in[6];
  const float* bb_in  = (const float*)d_in[7];
  const float* Wb_rec = (const float*)d_in[8];
  const float* Ub_z   = (const float*)d_in[9];
  const float* bb_u   = (const float*)d_in[10];

  char* ws = (char*)d_ws;
  const size_t BF = 33554432;                   // bytes of one bf16 [M_ x H_] buffer
  u16* xf  = (u16*)(ws + 0 * BF);               // x as bf16
  u16* z0  = (u16*)(ws + 1 * BF);               // z, dirs contiguous [2][M][H]
  u16* zu0 = (u16*)(ws + 3 * BF);               // zu, then zuh (in-place)
  u16* s10 = (u16*)(ws + 5 * BF);               // states1 shifted (+1 row), dirs contiguous
  u16* wbf = (u16*)(ws + 7 * BF);               // 6 x 256x256 bf16 weights
  char* pb = ws + 7 * BF + 1048576;
  float* Pbuf = (float*)(pb);                   // NCH*NCHAN f32 = 4 MB
  float* qbuf = (float*)(pb + 4194304);
  float* hst  = (float*)(pb + 8388608);
  (void)ws_size; (void)in_sizes; (void)n_in; (void)out_size;

  float* outp = (float*)d_out;                  // (B,T,512)
  float* hnp  = outp + (size_t)33554432;        // (2,B,256)

  dim3 gt(1024, 1, 2);

  prep_kernel<<<8384, 256, 0, stream>>>(x, xf, Wf_in, Uf_z, Wf_rec, Wb_in, Ub_z, Wb_rec, wbf);

  // z + zu + fused p1 (iter 1), one kernel
  zzu_k<<<gt, 256, 0, stream>>>(xf, wbf, bf_in, bb_in, bf_u, bb_u, Wf_rec, Wb_rec,
                                z0, zu0, Pbuf, qbuf);
  scan_p2_kernel<<<16, 256, 0, stream>>>(Pbuf, qbuf, hst);

  // p3<1> tile + zuh gemm + fused p1 (iter 2), one kernel
  s1zuh_k<<<gt, 256, 0, stream>>>(z0, zu0, wbf, Wf_rec, Wb_rec, hst, s10, Pbuf, qbuf);
  scan_p2_kernel<<<16, 256, 0, stream>>>(Pbuf, qbuf, hst);

  // final replay -> output + h_n
  scan_p3_kernel<<<1024, 256, 0, stream>>>(z0, zu0, s10, Wf_rec, Wb_rec, hst, outp, hnp);
}